// Round 3
// baseline (176.533 us; speedup 1.0000x reference)
//
#include <hip/hip_runtime.h>

// CG tensor product: 23 (l1,l2,L) triples, C=512. out = 99*C^2 fp32 (~104 MB).
// Block b: i = b>>2, j-half = (b>>1)&1, triple-half = b&1 (2048 blocks x 256).
// y[n,M] = sum_m cg[M,n,m]*xi[m] computed once per block into LDS rows padded
// to 8 floats (vectorizable ds_read_b64/b128). Thread owns one j: acc[M] =
// sum_n y[n,M]*xj[n], xj straight from global (x arrays are L1-resident),
// stores direct (wave-contiguous at L2 -> full-line HBM writes, proven r1==r2).

#define C2 (512 * 512)

struct Ptrs {
    const float* x[4];
    const float* cg[23];
};

// F(t, l1, l2, L, out_base_in_C2_units, y_row_base, triple_half)
#define TRIPLE_LIST(F) \
    F(0, 0, 0, 0, 0, 0, 0) \
    F(1, 0, 1, 1, 4, 1, 0) \
    F(2, 0, 2, 2, 22, 4, 1) \
    F(3, 0, 3, 3, 57, 9, 0) \
    F(4, 1, 1, 0, 1, 16, 0) \
    F(5, 1, 1, 1, 7, 19, 1) \
    F(6, 1, 1, 2, 27, 22, 1) \
    F(7, 1, 2, 1, 10, 25, 1) \
    F(8, 1, 2, 2, 32, 30, 1) \
    F(9, 1, 2, 3, 64, 35, 0) \
    F(10, 1, 3, 2, 37, 40, 1) \
    F(11, 1, 3, 3, 71, 47, 0) \
    F(12, 2, 2, 0, 2, 54, 0) \
    F(13, 2, 2, 1, 13, 59, 1) \
    F(14, 2, 2, 2, 42, 64, 1) \
    F(15, 2, 2, 3, 78, 69, 0) \
    F(16, 2, 3, 1, 16, 74, 1) \
    F(17, 2, 3, 2, 47, 81, 1) \
    F(18, 2, 3, 3, 85, 88, 0) \
    F(19, 3, 3, 0, 3, 95, 0) \
    F(20, 3, 3, 1, 19, 102, 1) \
    F(21, 3, 3, 2, 52, 109, 1) \
    F(22, 3, 3, 3, 92, 116, 0)

// xj register index base per l2: rows [x0 | x1(3) | x2(5) | x3(7)]
#define XBASE(L2) ((L2) == 0 ? 0 : ((L2) == 1 ? 1 : ((L2) == 2 ? 4 : 9)))

__global__ __launch_bounds__(256) void cg_tp_kernel(Ptrs p, float* __restrict__ out) {
    __shared__ float ysh[123 * 8];  // y rows (t,n) padded to 8 floats each

    const int tid = threadIdx.x;
    const int b = blockIdx.x;
    const int i = b >> 2;
    const int jh = (b >> 1) & 1;
    const int half = b & 1;
    const int j = (jh << 8) + tid;

    // ---- y fill: thread r < 123 computes row (t, n): ysh[r*8+M] = sum_m cg*xi ----
    if (tid < 123) {
        const int r = tid;
#define YC(T, L1, L2, LL, OB, RB, HF)                                          \
        if (r >= (RB) && r < (RB) + (2 * L2 + 1)) {                            \
            const int n = r - (RB);                                            \
            const float* cg = p.cg[T];                                         \
            const float* xi = p.x[L1] + i * (2 * L1 + 1);                      \
            _Pragma("unroll")                                                  \
            for (int M = 0; M < 2 * LL + 1; ++M) {                             \
                float s = 0.f;                                                 \
                _Pragma("unroll")                                              \
                for (int m = 0; m < 2 * L1 + 1; ++m)                           \
                    s = fmaf(cg[(M * (2 * L2 + 1) + n) * (2 * L1 + 1) + m],    \
                             xi[m], s);                                        \
                ysh[r * 8 + M] = s;                                            \
            }                                                                  \
        }
        TRIPLE_LIST(YC)
#undef YC
    }

    // ---- xj rows straight from global (x arrays are tiny -> L1-resident) ----
    float xj[16];
    {
        xj[0] = p.x[0][j];
        const float* x1 = p.x[1] + j * 3;
        #pragma unroll
        for (int m = 0; m < 3; ++m) xj[1 + m] = x1[m];
        const float* x2 = p.x[2] + j * 5;
        #pragma unroll
        for (int m = 0; m < 5; ++m) xj[4 + m] = x2[m];
        const float* x3 = p.x[3] + j * 7;
        #pragma unroll
        for (int m = 0; m < 7; ++m) xj[9 + m] = x3[m];
    }

    __syncthreads();

    const int pair = i * 512 + j;

    // ---- main: this block's triple-half only; direct dword stores ----
#define TC(T, L1, L2, LL, OB, RB, HF)                                          \
    if (half == (HF)) {                                                        \
        constexpr int NW = 2 * LL + 1;                                         \
        float acc[NW] = {};                                                    \
        const float* y = ysh + (RB) * 8;                                       \
        _Pragma("unroll")                                                      \
        for (int n = 0; n < 2 * L2 + 1; ++n) {                                 \
            const float xv = xj[XBASE(L2) + n];                                \
            _Pragma("unroll")                                                  \
            for (int M = 0; M < NW; ++M)                                       \
                acc[M] = fmaf(y[n * 8 + M], xv, acc[M]);                       \
        }                                                                      \
        float* o = out + (size_t)(OB) * C2 + (size_t)pair * NW;                \
        _Pragma("unroll")                                                      \
        for (int M = 0; M < NW; ++M) o[M] = acc[M];                            \
    }
    TRIPLE_LIST(TC)
#undef TC
}

extern "C" void kernel_launch(void* const* d_in, const int* in_sizes, int n_in,
                              void* d_out, int out_size, void* d_ws, size_t ws_size,
                              hipStream_t stream) {
    Ptrs p;
    for (int l = 0; l < 4; ++l) p.x[l] = (const float*)d_in[l];
    for (int t = 0; t < 23; ++t) p.cg[t] = (const float*)d_in[4 + t];
    cg_tp_kernel<<<dim3(2048), dim3(256), 0, stream>>>(p, (float*)d_out);
}